// Round 8
// baseline (148.317 us; speedup 1.0000x reference)
//
#include <hip/hip_runtime.h>

#define NF 16
#define HIDN 32
#define NB 32
#define NN 64
#define EPSV 1e-8f

typedef _Float16 f16x8 __attribute__((ext_vector_type(8)));
typedef _Float16 f16x2 __attribute__((ext_vector_type(2)));
typedef __fp16 fp16x2 __attribute__((ext_vector_type(2)));
typedef float f32x4 __attribute__((ext_vector_type(4)));

// Workspace layout (float offsets), all regions overwritten before read each call:
//   slotbits : 0       (16)    per-layer sigma bits
//   redzone  : 16      (512)   per-block absmax partials (update writes, pre reduces)
//   s        : 576     (32768)
//   vec      : 33344   (98304)
//   aggs     : 131648  (16*32768)
//   aggv     : 655936  (16*98304)
//   B2       : 2228800 (2048*128 fp32, sigma-scaled)
//   A2       : 2490944 (2048*4096 fp16, sigma-scaled)
#define SLOT_OFF 0
#define RED_OFF  16
#define S_OFF    576
#define VEC_OFF  33344
#define AGGS_OFF 131648
#define AGGV_OFF 655936
#define B2_OFF   2228800
#define A2_OFF   2490944

__device__ __forceinline__ void sigma_from_bits(unsigned mb, float* sig, float* invs) {
    int ex = (int)((mb >> 23) & 0xFF);
    if (ex == 0) { *sig = 1.f; *invs = 1.f; return; }
    *sig  = __uint_as_float((unsigned)(253 - ex) << 23);  // 2^(126-ex)
    *invs = __uint_as_float((unsigned)(ex + 1) << 23);    // 2^(ex-126)
}

__device__ __forceinline__ f16x2 cvt_pk(float a, float b) {
    fp16x2 r = __builtin_amdgcn_cvt_pkrtz(a, b);
    return __builtin_bit_cast(f16x2, r);
}

__device__ __forceinline__ f16x8 pack8(f16x2 a, f16x2 b, f16x2 c, f16x2 d) {
    f16x8 r;
    r[0] = a[0]; r[1] = a[1]; r[2] = b[0]; r[3] = b[1];
    r[4] = c[0]; r[5] = c[1]; r[6] = d[0]; r[7] = d[1];
    return r;
}

// grid 512 x 512 threads; 4 nodes/block. Thread (f=tid>>2, hq8=tid&3) owns an
// 8-h slice of one output row f for its block's 4 nodes.
template <int IS_L0>
__global__ __launch_bounds__(512) void k_pre(
        const float* __restrict__ z, const float* __restrict__ v,
        const float* __restrict__ w_s_in, const float* __restrict__ w_v_in,
        float* __restrict__ s, float* __restrict__ vec,
        const float* __restrict__ W2, const float* __restrict__ b2,
        const float* __restrict__ redzone, unsigned* __restrict__ slot_out,
        _Float16* __restrict__ A2, float* __restrict__ B2) {
    int node0 = (blockIdx.x >> 1) * 8 + (blockIdx.x & 1) * 4;
    int tid = threadIdx.x;
    __shared__ float s_sh[4][16];
    __shared__ float vec_t[3][4][16];   // transposed: [d][node][channel]
    __shared__ float red[512];

    float sigma, invs;
    {
        int k = tid >> 6, tt = tid & 63;
        int node = node0 + k;
        if (IS_L0) {
            sigma = 1.f; invs = 1.f;
            if (tid == 0 && blockIdx.x == 0) *slot_out = 0u;  // decodes sigma=1
            if (tid < 256) {
                if (tt < 16) {
                    float val = z[node] * w_s_in[tt];
                    s_sh[k][tt] = val;
                    s[node * 16 + tt] = val;
                } else {
                    int q = tt - 16, c = q / 3, d = q % 3;
                    float val = v[node * 3 + d] * w_v_in[c];
                    vec_t[d][k][c] = val;
                    vec[node * 48 + q] = val;
                }
            }
            __syncthreads();
        } else {
            red[tid] = redzone[tid];
            if (tid < 256) {
                if (tt < 16) s_sh[k][tt] = s[node * 16 + tt];
                else {
                    int q = tt - 16, c = q / 3, d = q % 3;
                    vec_t[d][k][c] = vec[node * 48 + q];
                }
            }
            __syncthreads();
#pragma unroll
            for (int o = 256; o > 0; o >>= 1) {
                if (tid < o) red[tid] = fmaxf(red[tid], red[tid + o]);
                __syncthreads();
            }
            unsigned mb = __float_as_uint(red[0]);
            sigma_from_bits(mb, &sigma, &invs);
            if (tid == 0) *slot_out = mb;
        }
    }

    int f = tid >> 2, hq8 = tid & 3;       // f 0..127, h-octet 0..3
    int i = f >> 3, cc = f & 7;
    int strm = (cc == 0) ? 0 : (cc == 1) ? 1 : (cc <= 4) ? 2 : 3;
    int dd = (cc <= 1) ? 0 : (cc <= 4 ? cc - 2 : cc - 5);
    const float* wp = W2 + (size_t)(hq8 * 8) * 1024 + strm * 256 + i * 16;

    float ft[4][16];
#pragma unroll
    for (int k2 = 0; k2 < 4; ++k2) {
        const float* srcp = (strm <= 1) ? &s_sh[k2][0] : &vec_t[dd][k2][0];
#pragma unroll
        for (int qq = 0; qq < 4; ++qq) {
            float4 x = *(const float4*)(srcp + qq * 4);
            ft[k2][qq * 4 + 0] = x.x; ft[k2][qq * 4 + 1] = x.y;
            ft[k2][qq * 4 + 2] = x.z; ft[k2][qq * 4 + 3] = x.w;
        }
    }
    float outv[4][8];
#pragma unroll
    for (int k2 = 0; k2 < 4; ++k2)
#pragma unroll
        for (int h8 = 0; h8 < 8; ++h8) outv[k2][h8] = 0.f;
#pragma unroll
    for (int h8 = 0; h8 < 8; ++h8) {
        const float4* w4 = (const float4*)(wp + h8 * 1024);
        float4 a0 = w4[0], a1 = w4[1], a2 = w4[2], a3 = w4[3];
        float w[16] = {a0.x,a0.y,a0.z,a0.w, a1.x,a1.y,a1.z,a1.w,
                       a2.x,a2.y,a2.z,a2.w, a3.x,a3.y,a3.z,a3.w};
#pragma unroll
        for (int k2 = 0; k2 < 4; ++k2) {
            float acc = 0.f;
#pragma unroll
            for (int j = 0; j < 16; ++j) acc += w[j] * ft[k2][j];
            outv[k2][h8] = acc;
        }
    }
#pragma unroll
    for (int k2 = 0; k2 < 4; ++k2) {
        f16x8 st;
#pragma unroll
        for (int h8 = 0; h8 < 8; ++h8) st[h8] = (_Float16)(outv[k2][h8] * sigma);
        *(f16x8*)(A2 + (size_t)(node0 + k2) * 4096 + f * 32 + hq8 * 8) = st;
    }
    if (hq8 == 0) {
        const float* bp = b2 + strm * 256 + i * 16;
        float bw[16];
#pragma unroll
        for (int qq = 0; qq < 4; ++qq) {
            float4 x = *(const float4*)(bp + qq * 4);
            bw[qq * 4 + 0] = x.x; bw[qq * 4 + 1] = x.y;
            bw[qq * 4 + 2] = x.z; bw[qq * 4 + 3] = x.w;
        }
#pragma unroll
        for (int k2 = 0; k2 < 4; ++k2) {
            float acc = 0.f;
#pragma unroll
            for (int j = 0; j < 16; ++j) acc += bw[j] * ft[k2][j];
            B2[(size_t)(node0 + k2) * 128 + f] = acc * sigma;
        }
    }
}

__global__ __launch_bounds__(256) void k_edge(
        const float* __restrict__ pos,
        const _Float16* __restrict__ A2, const float* __restrict__ B2,
        const float* __restrict__ w1, const float* __restrict__ b1,
        const unsigned* __restrict__ slot,
        float* __restrict__ aggs, float* __restrict__ aggv) {
    // grid 1024 = 8 xcd * 4 b * 16 sgrp * 2 fhalf; batch pinned to one XCD
    int blk = blockIdx.x;
    int xcd = blk & 7;
    int t = blk >> 3;                    // 0..127
    int b = xcd * 4 + (t >> 5);
    int rem = t & 31;
    int sgrp = rem >> 1, wfh = rem & 1;  // sgrp 0..15
    int wd = threadIdx.x >> 6;           // dst tile 0..3
    int lane = threadIdx.x & 63;
    int q = lane >> 4, col = lane & 15;
    int dst = wd * 16 + col;
    float qodd = (float)(q & 1);
    float o1 = qodd;

    __shared__ float pos_sh[NN * 3];
    if (threadIdx.x < NN * 3) pos_sh[threadIdx.x] = pos[(size_t)b * NN * 3 + threadIdx.x];
    __syncthreads();

    float pdx = pos_sh[dst * 3 + 0], pdy = pos_sh[dst * 3 + 1], pdz = pos_sh[dst * 3 + 2];
    float w1r[8], b1r[8];
#pragma unroll
    for (int j = 0; j < 8; ++j) { w1r[j] = w1[q * 8 + j]; b1r[j] = b1[q * 8 + j]; }

    float sigma, invs;
    sigma_from_bits(*slot, &sigma, &invs);

    f32x4 acc[4][4];
#pragma unroll
    for (int mt = 0; mt < 4; ++mt)
#pragma unroll
        for (int u = 0; u < 4; ++u) acc[mt][u] = (f32x4){0.f, 0.f, 0.f, 0.f};
    float ms_p[4] = {0.f, 0.f, 0.f, 0.f};
    float mv_p[4][3];
#pragma unroll
    for (int mt = 0; mt < 4; ++mt) { mv_p[mt][0] = 0.f; mv_p[mt][1] = 0.f; mv_p[mt][2] = 0.f; }

    const _Float16* Ab = A2 + (size_t)b * NN * 4096 + (size_t)wfh * 2048 + col * 32 + q * 8;
    const float* Bb = B2 + (size_t)b * NN * 128 + wfh * 64 + q * 4;

    for (int src = sgrp * 4; src < sgrp * 4 + 4; ++src) {
        float psx = pos_sh[src * 3 + 0];
        float psy = pos_sh[src * 3 + 1];
        float psz = pos_sh[src * 3 + 2];
        float dx = pdx - psx, dy = pdy - psy, dz = pdz - psz;
        float r = __builtin_amdgcn_sqrtf(dx * dx + dy * dy + dz * dz);
        float inv = __builtin_amdgcn_rcpf(r + EPSV);
        float ux = dx * inv, uy = dy * inv, uz = dz * inv;
        float vmask = (dst == src) ? 0.f : 1.f;

        // packed-f16 fragment build: h pairs via cvt_pkrtz, u-variants via pk_mul
        f16x2 vm2 = {(_Float16)vmask, (_Float16)vmask};
        f16x2 ux2 = {(_Float16)ux, (_Float16)ux};
        f16x2 uy2 = {(_Float16)uy, (_Float16)uy};
        f16x2 uz2 = {(_Float16)uz, (_Float16)uz};
        f16x2 p0[4], p1[4], p2[4], p3[4];
#pragma unroll
        for (int jp = 0; jp < 4; ++jp) {
            float h0 = fmaxf(fmaf(r, w1r[2 * jp],     b1r[2 * jp]),     0.f);
            float h1 = fmaxf(fmaf(r, w1r[2 * jp + 1], b1r[2 * jp + 1]), 0.f);
            f16x2 h2 = cvt_pk(h0, h1);
            p0[jp] = h2 * vm2;
            p1[jp] = p0[jp] * ux2;
            p2[jp] = p0[jp] * uy2;
            p3[jp] = p0[jp] * uz2;
        }
        f16x8 bf0 = pack8(p0[0], p0[1], p0[2], p0[3]);
        f16x8 bf1 = pack8(p1[0], p1[1], p1[2], p1[3]);
        f16x8 bf2 = pack8(p2[0], p2[1], p2[2], p2[3]);
        f16x8 bf3 = pack8(p3[0], p3[1], p3[2], p3[3]);

        const _Float16* Af = Ab + (size_t)src * 4096;
#pragma unroll
        for (int mt = 0; mt < 4; ++mt) {
            f16x8 af = *(const f16x8*)(Af + mt * 16 * 32);
            acc[mt][0] = __builtin_amdgcn_mfma_f32_16x16x32_f16(af, bf0, acc[mt][0], 0, 0, 0);
            acc[mt][1] = __builtin_amdgcn_mfma_f32_16x16x32_f16(af, bf1, acc[mt][1], 0, 0, 0);
            acc[mt][2] = __builtin_amdgcn_mfma_f32_16x16x32_f16(af, bf2, acc[mt][2], 0, 0, 0);
            acc[mt][3] = __builtin_amdgcn_mfma_f32_16x16x32_f16(af, bf3, acc[mt][3], 0, 0, 0);
        }

        float s0  = qodd ? uz : 1.f;
        float zx  = qodd ? 0.f : ux;
        float zy  = qodd ? 0.f : uy;
        float exu = qodd ? 1.f : ux;
        float euy = qodd ? 0.f : uy;
        float euz = qodd ? 0.f : uz;
        const float* Bf = Bb + (size_t)src * 128;
#pragma unroll
        for (int mt = 0; mt < 4; ++mt) {
            float4 bv = *(const float4*)(Bf + mt * 16);
            float t0 = bv.x * vmask, t1 = bv.y * vmask, t2 = bv.z * vmask, t3 = bv.w * vmask;
            ms_p[mt]    += t0 * s0 + t2 * zx + t3 * zy;
            mv_p[mt][0] += t1 * exu;
            mv_p[mt][1] += t1 * euy + t2 * o1;
            mv_p[mt][2] += t1 * euz + t3 * o1;
        }
    }

    if ((q & 1) == 0) {
#pragma unroll
        for (int mt = 0; mt < 4; ++mt) {
            ms_p[mt]    += acc[mt][0][0] + acc[mt][1][2] + acc[mt][2][3];
            mv_p[mt][0] += acc[mt][1][1];
            mv_p[mt][1] += acc[mt][2][1];
            mv_p[mt][2] += acc[mt][3][1];
        }
    } else {
#pragma unroll
        for (int mt = 0; mt < 4; ++mt) {
            ms_p[mt]    += acc[mt][3][0];
            mv_p[mt][0] += acc[mt][0][1];
            mv_p[mt][1] += acc[mt][0][2];
            mv_p[mt][2] += acc[mt][0][3];
        }
    }

#pragma unroll
    for (int mt = 0; mt < 4; ++mt) {
        ms_p[mt] = ms_p[mt] * invs + __shfl_xor(ms_p[mt] * invs, 16, 64);
        mv_p[mt][0] = mv_p[mt][0] * invs + __shfl_xor(mv_p[mt][0] * invs, 16, 64);
        mv_p[mt][1] = mv_p[mt][1] * invs + __shfl_xor(mv_p[mt][1] * invs, 16, 64);
        mv_p[mt][2] = mv_p[mt][2] * invs + __shfl_xor(mv_p[mt][2] * invs, 16, 64);
    }

    if ((q & 1) == 0) {
        int node = b * NN + dst;
#pragma unroll
        for (int mt = 0; mt < 4; ++mt) {
            int i2 = (wfh * 4 + mt) * 2 + (q >> 1);
            aggs[(size_t)sgrp * 32768 + node * 16 + i2] = ms_p[mt];
            float* vp = aggv + (size_t)sgrp * 98304 + node * 48 + i2 * 3;
            vp[0] = mv_p[mt][0]; vp[1] = mv_p[mt][1]; vp[2] = mv_p[mt][2];
        }
    }
}

__global__ __launch_bounds__(256) void k_update(
        const float* __restrict__ aggs, const float* __restrict__ aggv,
        const float* __restrict__ ws, const float* __restrict__ wv,
        float* __restrict__ s, float* __restrict__ vec, float* __restrict__ redzone) {
    int node0 = blockIdx.x * 4;
    int tid = threadIdx.x;
    int k = tid >> 6, tt = tid & 63;
    int node = node0 + k;
    __shared__ float ash[4][16];
    __shared__ float avh[4][48];
    if (tt < 16) {
        float a = 0.f;
#pragma unroll
        for (int p = 0; p < 16; ++p) a += aggs[(size_t)p * 32768 + node * 16 + tt];
        ash[k][tt] = a;
    } else {
        int qq = tt - 16;
        float a = 0.f;
#pragma unroll
        for (int p = 0; p < 16; ++p) a += aggv[(size_t)p * 98304 + node * 48 + qq];
        avh[k][qq] = a;
    }
    __syncthreads();
    float val;
    if (tt < 16) {
        float acc = 0.f;
#pragma unroll
        for (int c = 0; c < 16; ++c) acc += ash[k][c] * ws[c * 16 + tt];
        val = s[node * 16 + tt] + fmaxf(acc, 0.f);
        s[node * 16 + tt] = val;
    } else {
        int qq = tt - 16, e = qq / 3, d = qq % 3;
        float acc = 0.f;
#pragma unroll
        for (int c = 0; c < 16; ++c) acc += avh[k][c * 3 + d] * wv[c * 16 + e];
        val = vec[node * 48 + qq] + acc;
        vec[node * 48 + qq] = val;
    }
    __shared__ float red[256];
    red[tid] = fabsf(val);
    __syncthreads();
#pragma unroll
    for (int o = 128; o > 0; o >>= 1) {
        if (tid < o) red[tid] = fmaxf(red[tid], red[tid + o]);
        __syncthreads();
    }
    if (tid == 0) redzone[blockIdx.x] = red[0];
}

__global__ __launch_bounds__(256) void k_out(
        const float* __restrict__ aggv, const float* __restrict__ wv,
        const float* __restrict__ wvo, const float* __restrict__ vec,
        const float* __restrict__ pos, float* __restrict__ out) {
    int node0 = blockIdx.x * 4;
    int tid = threadIdx.x;
    int k = tid >> 6, t = tid & 63;
    int node = node0 + k;
    __shared__ float avh[4][48];
    __shared__ float vn[4][48];
    if (t < 48) {
        float a = 0.f;
#pragma unroll
        for (int p = 0; p < 16; ++p) a += aggv[(size_t)p * 98304 + node * 48 + t];
        avh[k][t] = a;
    }
    __syncthreads();
    if (t < 48) {
        int e = t / 3, d = t % 3;
        float acc = 0.f;
#pragma unroll
        for (int c = 0; c < 16; ++c) acc += avh[k][c * 3 + d] * wv[c * 16 + e];
        vn[k][t] = (vec[node * 48 + t] + acc) * wvo[e];
    }
    __syncthreads();
    if (t < 3) {
        float acc = 0.f;
#pragma unroll
        for (int e = 0; e < 16; ++e) acc += vn[k][e * 3 + t];
        out[node * 3 + t] = acc + pos[node * 3 + t];
    }
}

extern "C" void kernel_launch(void* const* d_in, const int* in_sizes, int n_in,
                              void* d_out, int out_size, void* d_ws, size_t ws_size,
                              hipStream_t stream) {
    const float* pos = (const float*)d_in[0];
    const float* v   = (const float*)d_in[1];
    const float* z   = (const float*)d_in[2];
    const float* w_s_in = (const float*)d_in[3];
    const float* w_v_in = (const float*)d_in[4];
    const float* rw1 = (const float*)d_in[5];
    const float* rb1 = (const float*)d_in[6];
    const float* rw2 = (const float*)d_in[7];
    const float* rb2 = (const float*)d_in[8];
    const float* sws = (const float*)d_in[9];
    const float* swv = (const float*)d_in[10];
    const float* wvo = (const float*)d_in[11];
    float* out = (float*)d_out;

    float* wsf  = (float*)d_ws;
    unsigned* slotbits = (unsigned*)(wsf + SLOT_OFF);
    float* redzone = wsf + RED_OFF;
    float* s    = wsf + S_OFF;
    float* vec  = wsf + VEC_OFF;
    float* aggs = wsf + AGGS_OFF;
    float* aggv = wsf + AGGV_OFF;
    float* B2   = wsf + B2_OFF;
    _Float16* A2 = (_Float16*)(wsf + A2_OFF);

    k_pre<1><<<512, 512, 0, stream>>>(z, v, w_s_in, w_v_in, s, vec,
                                      rw2, rb2, redzone, slotbits, A2, B2);
    k_edge<<<1024, 256, 0, stream>>>(pos, A2, B2, rw1, rb1, slotbits, aggs, aggv);

    k_update<<<512, 256, 0, stream>>>(aggs, aggv, sws, swv, s, vec, redzone);
    k_pre<0><<<512, 512, 0, stream>>>(z, v, w_s_in, w_v_in, s, vec,
                                      rw2 + 32768, rb2 + 1024, redzone, slotbits + 1, A2, B2);
    k_edge<<<1024, 256, 0, stream>>>(pos, A2, B2, rw1 + 32, rb1 + 32, slotbits + 1, aggs, aggv);

    k_update<<<512, 256, 0, stream>>>(aggs, aggv, sws + 256, swv + 256, s, vec, redzone);
    k_pre<0><<<512, 512, 0, stream>>>(z, v, w_s_in, w_v_in, s, vec,
                                      rw2 + 65536, rb2 + 2048, redzone, slotbits + 2, A2, B2);
    k_edge<<<1024, 256, 0, stream>>>(pos, A2, B2, rw1 + 64, rb1 + 64, slotbits + 2, aggs, aggv);

    k_out<<<512, 256, 0, stream>>>(aggv, swv + 512, wvo, vec, pos, out);
}

// Round 10
// 102.713 us; speedup vs baseline: 1.4440x; 1.4440x over previous
//
#include <hip/hip_runtime.h>

#define NF 16
#define HIDN 32
#define NB 32
#define NN 64
#define EPSV 1e-8f

typedef _Float16 f16x8 __attribute__((ext_vector_type(8)));
typedef _Float16 f16x2 __attribute__((ext_vector_type(2)));
typedef __fp16 fp16x2 __attribute__((ext_vector_type(2)));
typedef float f32x4 __attribute__((ext_vector_type(4)));

// Workspace layout (float offsets), all regions overwritten before read each call:
//   sigexp : 0       (2048 ints)  per-node scale exponent e (|inputs| < 2^e)
//   s      : 2048    (32768)
//   vec    : 34816   (98304)
//   aggs   : 133120  (8*32768)
//   aggv   : 395264  (8*98304)
//   B2     : 1181696 (2048*128 fp32, UNSCALED)
//   A2     : 1443840 (2048*4096 fp16, scaled by 2^-e_node)
#define SIG_OFF  0
#define S_OFF    2048
#define VEC_OFF  34816
#define AGGS_OFF 133120
#define AGGV_OFF 395264
#define B2_OFF   1181696
#define A2_OFF   1443840

__device__ __forceinline__ f16x2 cvt_pk(float a, float b) {
    fp16x2 r = __builtin_amdgcn_cvt_pkrtz(a, b);
    return __builtin_bit_cast(f16x2, r);
}

__device__ __forceinline__ f16x8 pack8(f16x2 a, f16x2 b, f16x2 c, f16x2 d) {
    f16x8 r;
    r[0] = a[0]; r[1] = a[1]; r[2] = b[0]; r[3] = b[1];
    r[4] = c[0]; r[5] = c[1]; r[6] = d[0]; r[7] = d[1];
    return r;
}

// Shared A2/B2 build: 512 threads, 8 nodes (2 passes of 4).
// Thread (f=tid>>2, hq8=tid&3) owns an 8-h slice of output row f.
__device__ __forceinline__ void pre_phaseB(
        int node0, int tid,
        const float (*s_sh)[16], const float (*vec_t)[8][16],
        const float* sigA_sh,
        const float* __restrict__ W2, const float* __restrict__ b2,
        _Float16* __restrict__ A2, float* __restrict__ B2) {
    int f = tid >> 2, hq8 = tid & 3;       // f 0..127, h-octet 0..3
    int i = f >> 3, cc = f & 7;
    int strm = (cc == 0) ? 0 : (cc == 1) ? 1 : (cc <= 4) ? 2 : 3;
    int dd = (cc <= 1) ? 0 : (cc <= 4 ? cc - 2 : cc - 5);
    const float* wp = W2 + (size_t)(hq8 * 8) * 1024 + strm * 256 + i * 16;

    float bw[16];
    if (hq8 == 0) {
        const float* bp = b2 + strm * 256 + i * 16;
#pragma unroll
        for (int qq = 0; qq < 4; ++qq) {
            float4 x = *(const float4*)(bp + qq * 4);
            bw[qq * 4 + 0] = x.x; bw[qq * 4 + 1] = x.y;
            bw[qq * 4 + 2] = x.z; bw[qq * 4 + 3] = x.w;
        }
    }

    for (int pass = 0; pass < 2; ++pass) {
        int kb = pass * 4;
        float ft[4][16];
#pragma unroll
        for (int k2 = 0; k2 < 4; ++k2) {
            const float* srcp = (strm <= 1) ? &s_sh[kb + k2][0] : &vec_t[dd][kb + k2][0];
#pragma unroll
            for (int qq = 0; qq < 4; ++qq) {
                float4 x = *(const float4*)(srcp + qq * 4);
                ft[k2][qq * 4 + 0] = x.x; ft[k2][qq * 4 + 1] = x.y;
                ft[k2][qq * 4 + 2] = x.z; ft[k2][qq * 4 + 3] = x.w;
            }
        }
        float outv[4][8];
#pragma unroll
        for (int k2 = 0; k2 < 4; ++k2)
#pragma unroll
            for (int h8 = 0; h8 < 8; ++h8) outv[k2][h8] = 0.f;
#pragma unroll
        for (int h8 = 0; h8 < 8; ++h8) {
            const float4* w4 = (const float4*)(wp + h8 * 1024);
            float4 a0 = w4[0], a1 = w4[1], a2 = w4[2], a3 = w4[3];
            float w[16] = {a0.x,a0.y,a0.z,a0.w, a1.x,a1.y,a1.z,a1.w,
                           a2.x,a2.y,a2.z,a2.w, a3.x,a3.y,a3.z,a3.w};
#pragma unroll
            for (int k2 = 0; k2 < 4; ++k2) {
                float acc = 0.f;
#pragma unroll
                for (int j = 0; j < 16; ++j) acc += w[j] * ft[k2][j];
                outv[k2][h8] = acc;
            }
        }
#pragma unroll
        for (int k2 = 0; k2 < 4; ++k2) {
            float sA = sigA_sh[kb + k2];
            f16x8 st;
#pragma unroll
            for (int h8 = 0; h8 < 8; ++h8) st[h8] = (_Float16)(outv[k2][h8] * sA);
            *(f16x8*)(A2 + (size_t)(node0 + kb + k2) * 4096 + f * 32 + hq8 * 8) = st;
        }
        if (hq8 == 0) {
#pragma unroll
            for (int k2 = 0; k2 < 4; ++k2) {
                float acc = 0.f;
#pragma unroll
                for (int j = 0; j < 16; ++j) acc += bw[j] * ft[k2][j];
                B2[(size_t)(node0 + kb + k2) * 128 + f] = acc;   // unscaled
            }
        }
    }
}

// grid 256 x 512: layer-0 init + A2/B2 build, per-node sigma (wave-local)
__global__ __launch_bounds__(512) void k_pre0(
        const float* __restrict__ z, const float* __restrict__ v,
        const float* __restrict__ w_s_in, const float* __restrict__ w_v_in,
        float* __restrict__ s, float* __restrict__ vec,
        const float* __restrict__ W2, const float* __restrict__ b2,
        int* __restrict__ sigexp, _Float16* __restrict__ A2, float* __restrict__ B2) {
    int node0 = blockIdx.x * 8;
    int tid = threadIdx.x;
    __shared__ float s_sh[8][16];
    __shared__ float vec_t[3][8][16];
    __shared__ float sigA_sh[8];

    int k = tid >> 6, tt = tid & 63;
    int node = node0 + k;
    float val;
    if (tt < 16) {
        val = z[node] * w_s_in[tt];
        s_sh[k][tt] = val;
        s[node * 16 + tt] = val;
    } else {
        int q = tt - 16, c = q / 3, d = q % 3;
        val = v[node * 3 + d] * w_v_in[c];
        vec_t[d][k][c] = val;
        vec[node * 48 + q] = val;
    }
    float m = fabsf(val);
#pragma unroll
    for (int off = 1; off < 64; off <<= 1) m = fmaxf(m, __shfl_xor(m, off));
    if (tt == 0) {
        unsigned mb = __float_as_uint(m);
        int ex = (int)((mb >> 23) & 0xFF);
        sigexp[node] = ex - 126;
        sigA_sh[k] = __uint_as_float((unsigned)(253 - ex) << 23);  // 2^-(ex-126)
    }
    __syncthreads();
    pre_phaseB(node0, tid, s_sh, vec_t, sigA_sh, W2, b2, A2, B2);
}

// grid 256 x 512: node update (agg reduce + self matmul + residual) fused with
// next layer's A2/B2 build; sigma is per-node wave-local (no global chain).
__global__ __launch_bounds__(512) void k_fused(
        const float* __restrict__ aggs, const float* __restrict__ aggv,
        const float* __restrict__ wsW, const float* __restrict__ wvW,
        float* __restrict__ s, float* __restrict__ vec,
        const float* __restrict__ W2, const float* __restrict__ b2,
        int* __restrict__ sigexp, _Float16* __restrict__ A2, float* __restrict__ B2) {
    int node0 = blockIdx.x * 8;
    int tid = threadIdx.x;
    __shared__ float ash[8][16];
    __shared__ float avh[8][48];
    __shared__ float s_sh[8][16];
    __shared__ float vec_t[3][8][16];
    __shared__ float sigA_sh[8];

    int k = tid >> 6, tt = tid & 63;
    int node = node0 + k;
    if (tt < 16) {
        float a = 0.f;
#pragma unroll
        for (int p = 0; p < 8; ++p) a += aggs[(size_t)p * 32768 + node * 16 + tt];
        ash[k][tt] = a;
    } else {
        int q = tt - 16;
        float a = 0.f;
#pragma unroll
        for (int p = 0; p < 8; ++p) a += aggv[(size_t)p * 98304 + node * 48 + q];
        avh[k][q] = a;
    }
    __syncthreads();
    float val;
    if (tt < 16) {
        float acc = 0.f;
#pragma unroll
        for (int c = 0; c < 16; ++c) acc += ash[k][c] * wsW[c * 16 + tt];
        val = s[node * 16 + tt] + fmaxf(acc, 0.f);
        s[node * 16 + tt] = val;
        s_sh[k][tt] = val;
    } else {
        int q = tt - 16, e2 = q / 3, d = q % 3;
        float acc = 0.f;
#pragma unroll
        for (int c = 0; c < 16; ++c) acc += avh[k][c * 3 + d] * wvW[c * 16 + e2];
        val = vec[node * 48 + q] + acc;
        vec[node * 48 + q] = val;
        vec_t[d][k][e2] = val;
    }
    float m = fabsf(val);
#pragma unroll
    for (int off = 1; off < 64; off <<= 1) m = fmaxf(m, __shfl_xor(m, off));
    if (tt == 0) {
        unsigned mb = __float_as_uint(m);
        int ex = (int)((mb >> 23) & 0xFF);
        sigexp[node] = ex - 126;
        sigA_sh[k] = __uint_as_float((unsigned)(253 - ex) << 23);
    }
    __syncthreads();
    pre_phaseB(node0, tid, s_sh, vec_t, sigA_sh, W2, b2, A2, B2);
}

__global__ __launch_bounds__(256) void k_edge(
        const float* __restrict__ pos,
        const _Float16* __restrict__ A2, const float* __restrict__ B2,
        const float* __restrict__ w1, const float* __restrict__ b1,
        const int* __restrict__ sigexp,
        float* __restrict__ aggs, float* __restrict__ aggv) {
    // grid 512 = 8 xcd * 4 b * 8 sgrp * 2 fhalf; batch pinned to one XCD
    int blk = blockIdx.x;
    int xcd = blk & 7;
    int t = blk >> 3;                    // 0..63
    int b = xcd * 4 + (t >> 4);
    int rem = t & 15;
    int sgrp = rem >> 1, wfh = rem & 1;
    int wd = threadIdx.x >> 6;           // dst tile 0..3
    int lane = threadIdx.x & 63;
    int q = lane >> 4, col = lane & 15;
    int dst = wd * 16 + col;
    float qodd = (float)(q & 1);
    float o1 = qodd;

    __shared__ float pos_sh[NN * 3];
    if (threadIdx.x < NN * 3) pos_sh[threadIdx.x] = pos[(size_t)b * NN * 3 + threadIdx.x];
    __syncthreads();

    float pdx = pos_sh[dst * 3 + 0], pdy = pos_sh[dst * 3 + 1], pdz = pos_sh[dst * 3 + 2];
    float w1r[8], b1r[8];
#pragma unroll
    for (int j = 0; j < 8; ++j) { w1r[j] = w1[q * 8 + j]; b1r[j] = b1[q * 8 + j]; }

    // per-src scale exponents; block max
    int ebase = b * NN + sgrp * 8;
    int es[8], eblk = -10000;
#pragma unroll
    for (int j = 0; j < 8; ++j) {
        es[j] = sigexp[ebase + j];
        eblk = es[j] > eblk ? es[j] : eblk;
    }
    float invsb = __uint_as_float((unsigned)(127 + eblk) << 23);  // 2^eblk

    f32x4 acc[4][4];
#pragma unroll
    for (int mt = 0; mt < 4; ++mt)
#pragma unroll
        for (int u = 0; u < 4; ++u) acc[mt][u] = (f32x4){0.f, 0.f, 0.f, 0.f};
    float ms_p[4] = {0.f, 0.f, 0.f, 0.f};
    float mv_p[4][3];
#pragma unroll
    for (int mt = 0; mt < 4; ++mt) { mv_p[mt][0] = 0.f; mv_p[mt][1] = 0.f; mv_p[mt][2] = 0.f; }

    const _Float16* Ab = A2 + (size_t)b * NN * 4096 + (size_t)wfh * 2048 + col * 32 + q * 8;
    const float* Bb = B2 + (size_t)b * NN * 128 + wfh * 64 + q * 4;

    for (int j = 0; j < 8; ++j) {
        int src = sgrp * 8 + j;
        float psx = pos_sh[src * 3 + 0];
        float psy = pos_sh[src * 3 + 1];
        float psz = pos_sh[src * 3 + 2];
        float dx = pdx - psx, dy = pdy - psy, dz = pdz - psz;
        float r = __builtin_amdgcn_sqrtf(dx * dx + dy * dy + dz * dz);
        float inv = __builtin_amdgcn_rcpf(r + EPSV);
        float ux = dx * inv, uy = dy * inv, uz = dz * inv;
        float vmask = (dst == src) ? 0.f : 1.f;

        int dEx = es[j] - eblk;
        float sc2 = (dEx < -120) ? 0.f : __uint_as_float((unsigned)(127 + dEx) << 23);
        float scl = sc2 * vmask;   // per-lane: masks self-edge, renorms per-src scale

        f16x2 ux2 = {(_Float16)ux, (_Float16)ux};
        f16x2 uy2 = {(_Float16)uy, (_Float16)uy};
        f16x2 uz2 = {(_Float16)uz, (_Float16)uz};
        f16x2 p0[4], p1[4], p2[4], p3[4];
#pragma unroll
        for (int jp = 0; jp < 4; ++jp) {
            float h0 = fmaxf(fmaf(r, w1r[2 * jp],     b1r[2 * jp]),     0.f) * scl;
            float h1 = fmaxf(fmaf(r, w1r[2 * jp + 1], b1r[2 * jp + 1]), 0.f) * scl;
            p0[jp] = cvt_pk(h0, h1);
            p1[jp] = p0[jp] * ux2;
            p2[jp] = p0[jp] * uy2;
            p3[jp] = p0[jp] * uz2;
        }
        f16x8 bf0 = pack8(p0[0], p0[1], p0[2], p0[3]);
        f16x8 bf1 = pack8(p1[0], p1[1], p1[2], p1[3]);
        f16x8 bf2 = pack8(p2[0], p2[1], p2[2], p2[3]);
        f16x8 bf3 = pack8(p3[0], p3[1], p3[2], p3[3]);

        const _Float16* Af = Ab + (size_t)src * 4096;
#pragma unroll
        for (int mt = 0; mt < 4; ++mt) {
            f16x8 af = *(const f16x8*)(Af + mt * 16 * 32);
            acc[mt][0] = __builtin_amdgcn_mfma_f32_16x16x32_f16(af, bf0, acc[mt][0], 0, 0, 0);
            acc[mt][1] = __builtin_amdgcn_mfma_f32_16x16x32_f16(af, bf1, acc[mt][1], 0, 0, 0);
            acc[mt][2] = __builtin_amdgcn_mfma_f32_16x16x32_f16(af, bf2, acc[mt][2], 0, 0, 0);
            acc[mt][3] = __builtin_amdgcn_mfma_f32_16x16x32_f16(af, bf3, acc[mt][3], 0, 0, 0);
        }

        // bias combine: B2 is UNSCALED fp32, accumulate at true scale
        float s0  = qodd ? uz : 1.f;
        float zx  = qodd ? 0.f : ux;
        float zy  = qodd ? 0.f : uy;
        float exu = qodd ? 1.f : ux;
        float euy = qodd ? 0.f : uy;
        float euz = qodd ? 0.f : uz;
        const float* Bf = Bb + (size_t)src * 128;
#pragma unroll
        for (int mt = 0; mt < 4; ++mt) {
            float4 bv = *(const float4*)(Bf + mt * 16);
            float t0 = bv.x * vmask, t1 = bv.y * vmask, t2 = bv.z * vmask, t3 = bv.w * vmask;
            ms_p[mt]    += t0 * s0 + t2 * zx + t3 * zy;
            mv_p[mt][0] += t1 * exu;
            mv_p[mt][1] += t1 * euy + t2 * o1;
            mv_p[mt][2] += t1 * euz + t3 * o1;
        }
    }

    // fold MFMA accumulators (scaled by 2^-eblk) into true-scale partials
#pragma unroll
    for (int mt = 0; mt < 4; ++mt) {
        float fs, fv0, fv1, fv2;
        if ((q & 1) == 0) {
            fs  = acc[mt][0][0] + acc[mt][1][2] + acc[mt][2][3];
            fv0 = acc[mt][1][1]; fv1 = acc[mt][2][1]; fv2 = acc[mt][3][1];
        } else {
            fs  = acc[mt][3][0];
            fv0 = acc[mt][0][1]; fv1 = acc[mt][0][2]; fv2 = acc[mt][0][3];
        }
        ms_p[mt]    += fs  * invsb;
        mv_p[mt][0] += fv0 * invsb;
        mv_p[mt][1] += fv1 * invsb;
        mv_p[mt][2] += fv2 * invsb;
    }

    // single xor-16 reduce: q pairs (0,1) and (2,3) hold complementary cc-streams
    // of the SAME output channel; q=0/q=2 then hold channels 2mt / 2mt+1.
#pragma unroll
    for (int mt = 0; mt < 4; ++mt) {
        ms_p[mt]    += __shfl_xor(ms_p[mt], 16, 64);
        mv_p[mt][0] += __shfl_xor(mv_p[mt][0], 16, 64);
        mv_p[mt][1] += __shfl_xor(mv_p[mt][1], 16, 64);
        mv_p[mt][2] += __shfl_xor(mv_p[mt][2], 16, 64);
    }

    if ((q & 1) == 0) {
        int node = b * NN + dst;
#pragma unroll
        for (int mt = 0; mt < 4; ++mt) {
            int i2 = (wfh * 4 + mt) * 2 + (q >> 1);
            aggs[(size_t)sgrp * 32768 + node * 16 + i2] = ms_p[mt];
            float* vp = aggv + (size_t)sgrp * 98304 + node * 48 + i2 * 3;
            vp[0] = mv_p[mt][0]; vp[1] = mv_p[mt][1]; vp[2] = mv_p[mt][2];
        }
    }
}

__global__ __launch_bounds__(256) void k_out(
        const float* __restrict__ aggv, const float* __restrict__ wv,
        const float* __restrict__ wvo, const float* __restrict__ vec,
        const float* __restrict__ pos, float* __restrict__ out) {
    int node0 = blockIdx.x * 4;
    int tid = threadIdx.x;
    int k = tid >> 6, t = tid & 63;
    int node = node0 + k;
    __shared__ float avh[4][48];
    __shared__ float vn[4][48];
    if (t < 48) {
        float a = 0.f;
#pragma unroll
        for (int p = 0; p < 8; ++p) a += aggv[(size_t)p * 98304 + node * 48 + t];
        avh[k][t] = a;
    }
    __syncthreads();
    if (t < 48) {
        int e = t / 3, d = t % 3;
        float acc = 0.f;
#pragma unroll
        for (int c = 0; c < 16; ++c) acc += avh[k][c * 3 + d] * wv[c * 16 + e];
        vn[k][t] = (vec[node * 48 + t] + acc) * wvo[e];
    }
    __syncthreads();
    if (t < 3) {
        float acc = 0.f;
#pragma unroll
        for (int e = 0; e < 16; ++e) acc += vn[k][e * 3 + t];
        out[node * 3 + t] = acc + pos[node * 3 + t];
    }
}

extern "C" void kernel_launch(void* const* d_in, const int* in_sizes, int n_in,
                              void* d_out, int out_size, void* d_ws, size_t ws_size,
                              hipStream_t stream) {
    const float* pos = (const float*)d_in[0];
    const float* v   = (const float*)d_in[1];
    const float* z   = (const float*)d_in[2];
    const float* w_s_in = (const float*)d_in[3];
    const float* w_v_in = (const float*)d_in[4];
    const float* rw1 = (const float*)d_in[5];
    const float* rb1 = (const float*)d_in[6];
    const float* rw2 = (const float*)d_in[7];
    const float* rb2 = (const float*)d_in[8];
    const float* sws = (const float*)d_in[9];
    const float* swv = (const float*)d_in[10];
    const float* wvo = (const float*)d_in[11];
    float* out = (float*)d_out;

    float* wsf  = (float*)d_ws;
    int* sigexp = (int*)(wsf + SIG_OFF);
    float* s    = wsf + S_OFF;
    float* vec  = wsf + VEC_OFF;
    float* aggs = wsf + AGGS_OFF;
    float* aggv = wsf + AGGV_OFF;
    float* B2   = wsf + B2_OFF;
    _Float16* A2 = (_Float16*)(wsf + A2_OFF);

    k_pre0<<<256, 512, 0, stream>>>(z, v, w_s_in, w_v_in, s, vec,
                                    rw2, rb2, sigexp, A2, B2);
    k_edge<<<512, 256, 0, stream>>>(pos, A2, B2, rw1, rb1, sigexp, aggs, aggv);

    k_fused<<<256, 512, 0, stream>>>(aggs, aggv, sws, swv, s, vec,
                                     rw2 + 32768, rb2 + 1024, sigexp, A2, B2);
    k_edge<<<512, 256, 0, stream>>>(pos, A2, B2, rw1 + 32, rb1 + 32, sigexp, aggs, aggv);

    k_fused<<<256, 512, 0, stream>>>(aggs, aggv, sws + 256, swv + 256, s, vec,
                                     rw2 + 65536, rb2 + 2048, sigexp, A2, B2);
    k_edge<<<512, 256, 0, stream>>>(pos, A2, B2, rw1 + 64, rb1 + 64, sigexp, aggs, aggv);

    k_out<<<512, 256, 0, stream>>>(aggv, swv + 512, wvo, vec, pos, out);
}

// Round 11
// 85.389 us; speedup vs baseline: 1.7370x; 1.2029x over previous
//
#include <hip/hip_runtime.h>

#define NF 16
#define NB 32
#define NN 64
#define EPSV 1e-8f

typedef _Float16 f16x8 __attribute__((ext_vector_type(8)));
typedef _Float16 f16x2 __attribute__((ext_vector_type(2)));
typedef __fp16 fp16x2 __attribute__((ext_vector_type(2)));
typedef float f32x4 __attribute__((ext_vector_type(4)));

// Workspace (float offsets), ping-pong buffers, all overwritten before read:
//   sA 0        vA 32768     (state after L0 init)
//   sB 131072   vB 163840    (state after L1 update)
//   aggsA 262144  aggvA 524288   (L0 partials; reused for L2)
//   aggsB 1310720 aggvB 1572864  (L1 partials)
#define SA_OFF    0
#define VA_OFF    32768
#define SB_OFF    131072
#define VB_OFF    163840
#define AGGSA_OFF 262144
#define AGGVA_OFF 524288
#define AGGSB_OFF 1310720
#define AGGVB_OFF 1572864

__device__ __forceinline__ f16x2 cvt_pk(float a, float b) {
    fp16x2 r = __builtin_amdgcn_cvt_pkrtz(a, b);
    return __builtin_bit_cast(f16x2, r);
}

__device__ __forceinline__ f16x8 pack8(f16x2 a, f16x2 b, f16x2 c, f16x2 d) {
    f16x8 r;
    r[0] = a[0]; r[1] = a[1]; r[2] = b[0]; r[3] = b[1];
    r[4] = c[0]; r[5] = c[1]; r[6] = d[0]; r[7] = d[1];
    return r;
}

// Merged per-layer kernel: [update from prev partials] + A2/B2 build (LDS) + edge.
// grid 512 = 8 xcd * 4 b * 8 sgrp * 2 fhalf; block owns 8 src nodes, all 64 dst.
template <int LAYER>
__global__ __launch_bounds__(256) void k_medge(
        const float* __restrict__ pos,
        const float* __restrict__ z, const float* __restrict__ v,
        const float* __restrict__ w_s_in, const float* __restrict__ w_v_in,
        const float* __restrict__ sws_l, const float* __restrict__ swv_l,
        const float* __restrict__ sprev, const float* __restrict__ vprev,
        float* __restrict__ snew, float* __restrict__ vnew,
        const float* __restrict__ aggs_in, const float* __restrict__ aggv_in,
        const float* __restrict__ W2, const float* __restrict__ b2,
        const float* __restrict__ w1, const float* __restrict__ b1,
        float* __restrict__ aggs_out, float* __restrict__ aggv_out) {
    int blk = blockIdx.x;
    int xcd = blk & 7;
    int t = blk >> 3;                    // 0..63
    int b = xcd * 4 + (t >> 4);
    int rem = t & 15;
    int sgrp = rem >> 1, wfh = rem & 1;
    int tid = threadIdx.x;
    int nbase = b * NN + sgrp * 8;       // this block's 8 src nodes

    __shared__ float pos_sh[NN * 3];
    __shared__ float s_sh[8][16];
    __shared__ float vec_t[3][8][16];    // [d][node][channel]
    __shared__ float aggfull[8][64];
    __shared__ float sigA_sh[8];
    __shared__ int eexp_sh[8];
    __shared__ _Float16 A2sh[8][2048];   // [src][chunk*8], chunk swizzled
    __shared__ float B2sh[8][64];

    if (tid < NN * 3) pos_sh[tid] = pos[(size_t)b * NN * 3 + tid];

    // ---- state phase: init (L0) or update from prev partials (L1,L2) ----
    if (LAYER == 0) {
        for (int it = tid; it < 512; it += 256) {
            int k = it >> 6, ch = it & 63;
            int node = nbase + k;
            if (ch < 16) {
                float val = z[node] * w_s_in[ch];
                s_sh[k][ch] = val;
                if (wfh == 0) snew[node * 16 + ch] = val;
            } else {
                int q = ch - 16, e = q / 3, d = q % 3;
                float val = v[node * 3 + d] * w_v_in[e];
                vec_t[d][k][e] = val;
                if (wfh == 0) vnew[node * 48 + q] = val;
            }
        }
    } else {
        for (int it = tid; it < 512; it += 256) {
            int k = it >> 6, ch = it & 63;
            int node = nbase + k;
            float a = 0.f;
            if (ch < 16) {
#pragma unroll
                for (int p = 0; p < 8; ++p) a += aggs_in[(size_t)p * 32768 + node * 16 + ch];
            } else {
#pragma unroll
                for (int p = 0; p < 8; ++p) a += aggv_in[(size_t)p * 98304 + node * 48 + (ch - 16)];
            }
            aggfull[k][ch] = a;
        }
        __syncthreads();
        for (int it = tid; it < 512; it += 256) {
            int k = it >> 6, ch = it & 63;
            int node = nbase + k;
            if (ch < 16) {
                float acc = 0.f;
#pragma unroll
                for (int c = 0; c < 16; ++c) acc += aggfull[k][c] * sws_l[c * 16 + ch];
                float val = sprev[node * 16 + ch] + fmaxf(acc, 0.f);
                s_sh[k][ch] = val;
                if (LAYER == 1 && wfh == 0) snew[node * 16 + ch] = val;
            } else {
                int q = ch - 16, e = q / 3, d = q % 3;
                float acc = 0.f;
#pragma unroll
                for (int c = 0; c < 16; ++c) acc += aggfull[k][16 + c * 3 + d] * swv_l[c * 16 + e];
                float val = vprev[node * 48 + q] + acc;
                vec_t[d][k][e] = val;
                if (LAYER == 1 && wfh == 0) vnew[node * 48 + q] = val;
            }
        }
    }
    __syncthreads();

    // ---- per-node scale exponent (block-local) ----
    if (tid < 8) {
        float m = 0.f;
#pragma unroll
        for (int j = 0; j < 16; ++j) m = fmaxf(m, fabsf(s_sh[tid][j]));
#pragma unroll
        for (int d = 0; d < 3; ++d)
#pragma unroll
            for (int e = 0; e < 16; ++e) m = fmaxf(m, fabsf(vec_t[d][tid][e]));
        unsigned mb = __float_as_uint(m);
        int ex = (int)((mb >> 23) & 0xFF);
        eexp_sh[tid] = ex - 126;
        sigA_sh[tid] = __uint_as_float((unsigned)(253 - ex) << 23);  // 2^(126-ex)
    }
    __syncthreads();

    // ---- pre phase: build this block's A2/B2 half into LDS ----
    {
        int fh = tid >> 2, hq8 = tid & 3;      // fh 0..63 within half
        int fg = wfh * 64 + fh;
        int i = fg >> 3, cc = fg & 7;
        int strm = (cc == 0) ? 0 : (cc == 1) ? 1 : (cc <= 4) ? 2 : 3;
        int dd = (cc <= 1) ? 0 : (cc <= 4 ? cc - 2 : cc - 5);
        const float* wp = W2 + (size_t)(hq8 * 8) * 1024 + strm * 256 + i * 16;
        int mt = fh >> 4, colw = fh & 15;
        int chunk = mt * 64 + hq8 * 16 + ((colw + hq8 * 4) & 15);  // bank swizzle

        float bw[16];
        if (hq8 == 0) {
            const float* bp = b2 + strm * 256 + i * 16;
#pragma unroll
            for (int qq = 0; qq < 4; ++qq) {
                float4 x = *(const float4*)(bp + qq * 4);
                bw[qq * 4 + 0] = x.x; bw[qq * 4 + 1] = x.y;
                bw[qq * 4 + 2] = x.z; bw[qq * 4 + 3] = x.w;
            }
        }

        for (int pass = 0; pass < 2; ++pass) {
            int kb = pass * 4;
            float ft[4][16];
#pragma unroll
            for (int k2 = 0; k2 < 4; ++k2) {
                const float* srcp = (strm <= 1) ? &s_sh[kb + k2][0] : &vec_t[dd][kb + k2][0];
#pragma unroll
                for (int qq = 0; qq < 4; ++qq) {
                    float4 x = *(const float4*)(srcp + qq * 4);
                    ft[k2][qq * 4 + 0] = x.x; ft[k2][qq * 4 + 1] = x.y;
                    ft[k2][qq * 4 + 2] = x.z; ft[k2][qq * 4 + 3] = x.w;
                }
            }
            float outv[4][8];
#pragma unroll
            for (int k2 = 0; k2 < 4; ++k2)
#pragma unroll
                for (int h8 = 0; h8 < 8; ++h8) outv[k2][h8] = 0.f;
#pragma unroll
            for (int h8 = 0; h8 < 8; ++h8) {
                const float4* w4 = (const float4*)(wp + h8 * 1024);
                float4 a0 = w4[0], a1 = w4[1], a2 = w4[2], a3 = w4[3];
                float w[16] = {a0.x,a0.y,a0.z,a0.w, a1.x,a1.y,a1.z,a1.w,
                               a2.x,a2.y,a2.z,a2.w, a3.x,a3.y,a3.z,a3.w};
#pragma unroll
                for (int k2 = 0; k2 < 4; ++k2) {
                    float acc = 0.f;
#pragma unroll
                    for (int j = 0; j < 16; ++j) acc += w[j] * ft[k2][j];
                    outv[k2][h8] = acc;
                }
            }
#pragma unroll
            for (int k2 = 0; k2 < 4; ++k2) {
                float sA = sigA_sh[kb + k2];
                f16x8 st;
#pragma unroll
                for (int h8 = 0; h8 < 8; ++h8) st[h8] = (_Float16)(outv[k2][h8] * sA);
                *(f16x8*)&A2sh[kb + k2][chunk * 8] = st;
            }
            if (hq8 == 0) {
#pragma unroll
                for (int k2 = 0; k2 < 4; ++k2) {
                    float acc = 0.f;
#pragma unroll
                    for (int j = 0; j < 16; ++j) acc += bw[j] * ft[k2][j];
                    B2sh[kb + k2][fh] = acc;   // unscaled
                }
            }
        }
    }
    __syncthreads();

    // ---- edge phase: 4 waves x 16 dst cols, MFMA over 8 srcs from LDS ----
    {
        int wd = tid >> 6;
        int lane = tid & 63;
        int q = lane >> 4, col = lane & 15;
        int dst = wd * 16 + col;
        float qodd = (float)(q & 1);
        float o1 = qodd;

        float pdx = pos_sh[dst * 3 + 0], pdy = pos_sh[dst * 3 + 1], pdz = pos_sh[dst * 3 + 2];
        float w1r[8], b1r[8];
#pragma unroll
        for (int j = 0; j < 8; ++j) { w1r[j] = w1[q * 8 + j]; b1r[j] = b1[q * 8 + j]; }

        int es[8], eblk = -10000;
#pragma unroll
        for (int j = 0; j < 8; ++j) {
            es[j] = eexp_sh[j];
            eblk = es[j] > eblk ? es[j] : eblk;
        }
        float invsb = __uint_as_float((unsigned)(127 + eblk) << 23);  // 2^eblk

        f32x4 acc[4][4];
#pragma unroll
        for (int mt = 0; mt < 4; ++mt)
#pragma unroll
            for (int u = 0; u < 4; ++u) acc[mt][u] = (f32x4){0.f, 0.f, 0.f, 0.f};
        float ms_p[4] = {0.f, 0.f, 0.f, 0.f};
        float mv_p[4][3];
#pragma unroll
        for (int mt = 0; mt < 4; ++mt) { mv_p[mt][0] = 0.f; mv_p[mt][1] = 0.f; mv_p[mt][2] = 0.f; }

        for (int j = 0; j < 8; ++j) {
            int src = sgrp * 8 + j;
            float psx = pos_sh[src * 3 + 0];
            float psy = pos_sh[src * 3 + 1];
            float psz = pos_sh[src * 3 + 2];
            float dx = pdx - psx, dy = pdy - psy, dz = pdz - psz;
            float r = __builtin_amdgcn_sqrtf(dx * dx + dy * dy + dz * dz);
            float inv = __builtin_amdgcn_rcpf(r + EPSV);
            float ux = dx * inv, uy = dy * inv, uz = dz * inv;
            float vmask = (dst == src) ? 0.f : 1.f;

            int dEx = es[j] - eblk;
            float sc2 = (dEx < -120) ? 0.f : __uint_as_float((unsigned)(127 + dEx) << 23);
            float scl = sc2 * vmask;

            f16x2 ux2 = {(_Float16)ux, (_Float16)ux};
            f16x2 uy2 = {(_Float16)uy, (_Float16)uy};
            f16x2 uz2 = {(_Float16)uz, (_Float16)uz};
            f16x2 p0[4], p1[4], p2[4], p3[4];
#pragma unroll
            for (int jp = 0; jp < 4; ++jp) {
                float h0 = fmaxf(fmaf(r, w1r[2 * jp],     b1r[2 * jp]),     0.f) * scl;
                float h1 = fmaxf(fmaf(r, w1r[2 * jp + 1], b1r[2 * jp + 1]), 0.f) * scl;
                p0[jp] = cvt_pk(h0, h1);
                p1[jp] = p0[jp] * ux2;
                p2[jp] = p0[jp] * uy2;
                p3[jp] = p0[jp] * uz2;
            }
            f16x8 bf0 = pack8(p0[0], p0[1], p0[2], p0[3]);
            f16x8 bf1 = pack8(p1[0], p1[1], p1[2], p1[3]);
            f16x8 bf2 = pack8(p2[0], p2[1], p2[2], p2[3]);
            f16x8 bf3 = pack8(p3[0], p3[1], p3[2], p3[3]);

#pragma unroll
            for (int mt = 0; mt < 4; ++mt) {
                f16x8 af = *(const f16x8*)&A2sh[j][(mt * 64 + q * 16 + ((col + q * 4) & 15)) * 8];
                acc[mt][0] = __builtin_amdgcn_mfma_f32_16x16x32_f16(af, bf0, acc[mt][0], 0, 0, 0);
                acc[mt][1] = __builtin_amdgcn_mfma_f32_16x16x32_f16(af, bf1, acc[mt][1], 0, 0, 0);
                acc[mt][2] = __builtin_amdgcn_mfma_f32_16x16x32_f16(af, bf2, acc[mt][2], 0, 0, 0);
                acc[mt][3] = __builtin_amdgcn_mfma_f32_16x16x32_f16(af, bf3, acc[mt][3], 0, 0, 0);
            }

            float s0  = qodd ? uz : 1.f;
            float zx  = qodd ? 0.f : ux;
            float zy  = qodd ? 0.f : uy;
            float exu = qodd ? 1.f : ux;
            float euy = qodd ? 0.f : uy;
            float euz = qodd ? 0.f : uz;
#pragma unroll
            for (int mt = 0; mt < 4; ++mt) {
                float4 bv = *(const float4*)&B2sh[j][mt * 16 + q * 4];
                float t0 = bv.x * vmask, t1 = bv.y * vmask, t2 = bv.z * vmask, t3 = bv.w * vmask;
                ms_p[mt]    += t0 * s0 + t2 * zx + t3 * zy;
                mv_p[mt][0] += t1 * exu;
                mv_p[mt][1] += t1 * euy + t2 * o1;
                mv_p[mt][2] += t1 * euz + t3 * o1;
            }
        }

#pragma unroll
        for (int mt = 0; mt < 4; ++mt) {
            float fs, fv0, fv1, fv2;
            if ((q & 1) == 0) {
                fs  = acc[mt][0][0] + acc[mt][1][2] + acc[mt][2][3];
                fv0 = acc[mt][1][1]; fv1 = acc[mt][2][1]; fv2 = acc[mt][3][1];
            } else {
                fs  = acc[mt][3][0];
                fv0 = acc[mt][0][1]; fv1 = acc[mt][0][2]; fv2 = acc[mt][0][3];
            }
            ms_p[mt]    += fs  * invsb;
            mv_p[mt][0] += fv0 * invsb;
            mv_p[mt][1] += fv1 * invsb;
            mv_p[mt][2] += fv2 * invsb;
        }

        // single xor-16 reduce (q pairs hold complementary cc-streams of same channel)
#pragma unroll
        for (int mt = 0; mt < 4; ++mt) {
            ms_p[mt]    += __shfl_xor(ms_p[mt], 16, 64);
            mv_p[mt][0] += __shfl_xor(mv_p[mt][0], 16, 64);
            mv_p[mt][1] += __shfl_xor(mv_p[mt][1], 16, 64);
            mv_p[mt][2] += __shfl_xor(mv_p[mt][2], 16, 64);
        }

        if ((q & 1) == 0) {
            int node = b * NN + dst;
#pragma unroll
            for (int mt = 0; mt < 4; ++mt) {
                int i2 = (wfh * 4 + mt) * 2 + (q >> 1);
                aggs_out[(size_t)sgrp * 32768 + node * 16 + i2] = ms_p[mt];
                float* vp = aggv_out + (size_t)sgrp * 98304 + node * 48 + i2 * 3;
                vp[0] = mv_p[mt][0]; vp[1] = mv_p[mt][1]; vp[2] = mv_p[mt][2];
            }
        }
    }
}

__global__ __launch_bounds__(256) void k_out(
        const float* __restrict__ aggv, const float* __restrict__ wv,
        const float* __restrict__ wvo, const float* __restrict__ vec,
        const float* __restrict__ pos, float* __restrict__ out) {
    int node0 = blockIdx.x * 4;
    int tid = threadIdx.x;
    int k = tid >> 6, t = tid & 63;
    int node = node0 + k;
    __shared__ float avh[4][48];
    __shared__ float vn[4][48];
    if (t < 48) {
        float a = 0.f;
#pragma unroll
        for (int p = 0; p < 8; ++p) a += aggv[(size_t)p * 98304 + node * 48 + t];
        avh[k][t] = a;
    }
    __syncthreads();
    if (t < 48) {
        int e = t / 3, d = t % 3;
        float acc = 0.f;
#pragma unroll
        for (int c = 0; c < 16; ++c) acc += avh[k][c * 3 + d] * wv[c * 16 + e];
        vn[k][t] = (vec[node * 48 + t] + acc) * wvo[e];
    }
    __syncthreads();
    if (t < 3) {
        float acc = 0.f;
#pragma unroll
        for (int e = 0; e < 16; ++e) acc += vn[k][e * 3 + t];
        out[node * 3 + t] = acc + pos[node * 3 + t];
    }
}

extern "C" void kernel_launch(void* const* d_in, const int* in_sizes, int n_in,
                              void* d_out, int out_size, void* d_ws, size_t ws_size,
                              hipStream_t stream) {
    const float* pos = (const float*)d_in[0];
    const float* v   = (const float*)d_in[1];
    const float* z   = (const float*)d_in[2];
    const float* w_s_in = (const float*)d_in[3];
    const float* w_v_in = (const float*)d_in[4];
    const float* rw1 = (const float*)d_in[5];
    const float* rb1 = (const float*)d_in[6];
    const float* rw2 = (const float*)d_in[7];
    const float* rb2 = (const float*)d_in[8];
    const float* sws = (const float*)d_in[9];
    const float* swv = (const float*)d_in[10];
    const float* wvo = (const float*)d_in[11];
    float* out = (float*)d_out;

    float* wsf = (float*)d_ws;
    float* sA = wsf + SA_OFF;
    float* vA = wsf + VA_OFF;
    float* sB = wsf + SB_OFF;
    float* vB = wsf + VB_OFF;
    float* aggsA = wsf + AGGSA_OFF;
    float* aggvA = wsf + AGGVA_OFF;
    float* aggsB = wsf + AGGSB_OFF;
    float* aggvB = wsf + AGGVB_OFF;

    // L0: init state -> sA/vA, edge -> aggsA/aggvA
    k_medge<0><<<512, 256, 0, stream>>>(pos, z, v, w_s_in, w_v_in,
                                        sws, swv, sA, vA, sA, vA,
                                        aggsB, aggvB,
                                        rw2, rb2, rw1, rb1,
                                        aggsA, aggvA);
    // L1: update(aggsA)+residual(sA) -> sB/vB, edge -> aggsB/aggvB
    k_medge<1><<<512, 256, 0, stream>>>(pos, z, v, w_s_in, w_v_in,
                                        sws, swv, sA, vA, sB, vB,
                                        aggsA, aggvA,
                                        rw2 + 32768, rb2 + 1024, rw1 + 32, rb1 + 32,
                                        aggsB, aggvB);
    // L2: update(aggsB)+residual(sB) (no state write), edge -> aggsA/aggvA
    k_medge<2><<<512, 256, 0, stream>>>(pos, z, v, w_s_in, w_v_in,
                                        sws + 256, swv + 256, sB, vB, sA, vA,
                                        aggsB, aggvB,
                                        rw2 + 65536, rb2 + 2048, rw1 + 64, rb1 + 64,
                                        aggsA, aggvA);
    // out: vec_L1 (vB) + L2 partials (aggvA)
    k_out<<<512, 256, 0, stream>>>(aggvA, swv + 512, wvo, vB, pos, out);
}